// Round 1
// baseline (1845.790 us; speedup 1.0000x reference)
//
#include <hip/hip_runtime.h>
#include <hip/hip_bf16.h>
#include <cstdint>

// ---------------------------------------------------------------------------
// Decoder step: emb lookup + additive attention + gated context + LSTMCell +
// deepout. All GEMMs via bf16 MFMA 16x16x32 (no fp32 MFMA on CDNA4).
// Outputs concatenated in d_out: [logit 256x10000][new_h 256x1024]
// [new_c 256x1024][alpha 256x196], all f32.
// ---------------------------------------------------------------------------

typedef __attribute__((ext_vector_type(8))) short short8;
typedef __attribute__((ext_vector_type(4))) float f32x4;

#define BM 128
#define BN 128
#define BK 32
#define LDT 56   // LDS row stride in bf16 elems: 112 B, 16B-aligned, non-pow2 banks

static __device__ inline unsigned short f2bf(float x) {
    // round-to-nearest-even f32 -> bf16
    uint32_t u = __builtin_bit_cast(uint32_t, x);
    u = (u + 0x7FFFu + ((u >> 16) & 1u)) >> 16;
    return (unsigned short)u;
}

static __device__ inline uint64_t pack4(f32x4 v) {
    return (uint64_t)f2bf(v.x) | ((uint64_t)f2bf(v.y) << 16) |
           ((uint64_t)f2bf(v.z) << 32) | ((uint64_t)f2bf(v.w) << 48);
}

static __device__ inline float sigf(float x) { return 1.0f / (1.0f + expf(-x)); }

// ---------------------------------------------------------------------------
// Generic NT GEMM: C[m,n] = sum_k A[m,k]*W[n,k] (+bias[n]) (+C_old if accflag)
// A: [M,K] row-major f32, W: [N,K] row-major f32. 128x128 tile, 4 waves,
// each wave 64x64 via 4x4 grid of 16x16x32 bf16 MFMAs.
// ---------------------------------------------------------------------------
__global__ __launch_bounds__(256) void gemm_nt(
    const float* __restrict__ A, const float* __restrict__ W,
    const float* __restrict__ bias, float* __restrict__ C,
    int M, int N, int K, int accflag)
{
    __shared__ unsigned short As[BM * LDT];
    __shared__ unsigned short Ws[BN * LDT];
    const int tid  = threadIdx.x;
    const int lane = tid & 63;
    const int wid  = tid >> 6;
    const int wm   = (wid >> 1) * 64;
    const int wn   = (wid & 1) * 64;
    const int m0   = blockIdx.y * BM;
    const int n0   = blockIdx.x * BN;

    f32x4 acc[4][4];
#pragma unroll
    for (int i = 0; i < 4; ++i)
#pragma unroll
        for (int j = 0; j < 4; ++j) acc[i][j] = (f32x4){0.f, 0.f, 0.f, 0.f};

    for (int k0 = 0; k0 < K; k0 += BK) {
#pragma unroll
        for (int i = 0; i < 4; ++i) {
            int idx = i * 256 + tid;
            int rr = idx >> 3;   // 0..127
            int cq = idx & 7;    // float4 index within the 32-wide K slab
            int gm = m0 + rr;
            f32x4 va = (f32x4){0.f, 0.f, 0.f, 0.f};
            if (gm < M) va = *(const f32x4*)(A + (size_t)gm * K + k0 + cq * 4);
            *(uint64_t*)&As[rr * LDT + cq * 4] = pack4(va);
            int gn = n0 + rr;
            f32x4 vb = (f32x4){0.f, 0.f, 0.f, 0.f};
            if (gn < N) vb = *(const f32x4*)(W + (size_t)gn * K + k0 + cq * 4);
            *(uint64_t*)&Ws[rr * LDT + cq * 4] = pack4(vb);
        }
        __syncthreads();
        const int kq = lane >> 4;   // k-octet: k = kq*8 + j
        const int fr = lane & 15;   // row (A) / col (B)
        short8 af[4], bw[4];
#pragma unroll
        for (int mi = 0; mi < 4; ++mi)
            af[mi] = *(const short8*)&As[(wm + mi * 16 + fr) * LDT + kq * 8];
#pragma unroll
        for (int ni = 0; ni < 4; ++ni)
            bw[ni] = *(const short8*)&Ws[(wn + ni * 16 + fr) * LDT + kq * 8];
#pragma unroll
        for (int mi = 0; mi < 4; ++mi)
#pragma unroll
            for (int ni = 0; ni < 4; ++ni)
                acc[mi][ni] = __builtin_amdgcn_mfma_f32_16x16x32_bf16(
                    af[mi], bw[ni], acc[mi][ni], 0, 0, 0);
        __syncthreads();
    }
    // epilogue: C/D layout col=lane&15, row=(lane>>4)*4+reg  [m89/m91-verified]
    const int cr = (lane >> 4) * 4;
    const int cc = lane & 15;
#pragma unroll
    for (int mi = 0; mi < 4; ++mi)
#pragma unroll
        for (int ni = 0; ni < 4; ++ni) {
            int gn = n0 + wn + ni * 16 + cc;
#pragma unroll
            for (int r = 0; r < 4; ++r) {
                int gm = m0 + wm + mi * 16 + cr + r;
                if (gm < M && gn < N) {
                    float v = acc[mi][ni][r];
                    if (bias) v += bias[gn];
                    if (accflag) v += C[(size_t)gm * N + gn];
                    C[(size_t)gm * N + gn] = v;
                }
            }
        }
}

// ---------------------------------------------------------------------------
// Fused score GEMM: score[m] = sum_a relu(feat[m,:]@Wf[a,:] + bf[a] +
// hid_proj[b,a]) * Wa[a],  m = b*196+l.  M=50176, N=1024 (8 N-tile blocks,
// atomicAdd the partial row sums), K=2048.
// ---------------------------------------------------------------------------
__global__ __launch_bounds__(256) void score_gemm(
    const float* __restrict__ A,      // features [50176,2048]
    const float* __restrict__ W,      // att_Wf [1024,2048]
    const float* __restrict__ bfb,    // att_bf [1024]
    const float* __restrict__ hproj,  // [256,1024]
    const float* __restrict__ Wa,     // [1024]
    float* __restrict__ score)        // [50176], pre-zeroed
{
    const int M = 50176, N = 1024, K = 2048;
    __shared__ unsigned short As[BM * LDT];
    __shared__ unsigned short Ws[BN * LDT];
    const int tid  = threadIdx.x;
    const int lane = tid & 63;
    const int wid  = tid >> 6;
    const int wm   = (wid >> 1) * 64;
    const int wn   = (wid & 1) * 64;
    const int m0   = blockIdx.y * BM;
    const int n0   = blockIdx.x * BN;

    f32x4 acc[4][4];
#pragma unroll
    for (int i = 0; i < 4; ++i)
#pragma unroll
        for (int j = 0; j < 4; ++j) acc[i][j] = (f32x4){0.f, 0.f, 0.f, 0.f};

    for (int k0 = 0; k0 < K; k0 += BK) {
#pragma unroll
        for (int i = 0; i < 4; ++i) {
            int idx = i * 256 + tid;
            int rr = idx >> 3;
            int cq = idx & 7;
            f32x4 va = *(const f32x4*)(A + (size_t)(m0 + rr) * K + k0 + cq * 4);
            *(uint64_t*)&As[rr * LDT + cq * 4] = pack4(va);
            f32x4 vb = *(const f32x4*)(W + (size_t)(n0 + rr) * K + k0 + cq * 4);
            *(uint64_t*)&Ws[rr * LDT + cq * 4] = pack4(vb);
        }
        __syncthreads();
        const int kq = lane >> 4;
        const int fr = lane & 15;
        short8 af[4], bw[4];
#pragma unroll
        for (int mi = 0; mi < 4; ++mi)
            af[mi] = *(const short8*)&As[(wm + mi * 16 + fr) * LDT + kq * 8];
#pragma unroll
        for (int ni = 0; ni < 4; ++ni)
            bw[ni] = *(const short8*)&Ws[(wn + ni * 16 + fr) * LDT + kq * 8];
#pragma unroll
        for (int mi = 0; mi < 4; ++mi)
#pragma unroll
            for (int ni = 0; ni < 4; ++ni)
                acc[mi][ni] = __builtin_amdgcn_mfma_f32_16x16x32_bf16(
                    af[mi], bw[ni], acc[mi][ni], 0, 0, 0);
        __syncthreads();
    }
    const int cr = (lane >> 4) * 4;
    const int cc = lane & 15;
#pragma unroll
    for (int mi = 0; mi < 4; ++mi)
#pragma unroll
        for (int r = 0; r < 4; ++r) {
            int gm = m0 + wm + mi * 16 + cr + r;
            int b  = gm / 196;
            float s = 0.f;
#pragma unroll
            for (int ni = 0; ni < 4; ++ni) {
                int gn = n0 + wn + ni * 16 + cc;
                float v = acc[mi][ni][r] + bfb[gn] + hproj[b * 1024 + gn];
                v = fmaxf(v, 0.f);
                s += v * Wa[gn];
            }
            // reduce over the 16 lane-columns (xor masks <16 stay in-group)
            s += __shfl_xor(s, 1);
            s += __shfl_xor(s, 2);
            s += __shfl_xor(s, 4);
            s += __shfl_xor(s, 8);
            if (cc == 0) atomicAdd(&score[gm], s);
        }
}

// softmax over L=196 per batch row -> alpha
__global__ void softmax_alpha(const float* __restrict__ score, float* __restrict__ alpha) {
    int b = blockIdx.x;
    int t = threadIdx.x;  // 256
    __shared__ float red[256];
    float v = (t < 196) ? score[b * 196 + t] : -1e30f;
    red[t] = v;
    __syncthreads();
    for (int s = 128; s > 0; s >>= 1) {
        if (t < s) red[t] = fmaxf(red[t], red[t + s]);
        __syncthreads();
    }
    float mx = red[0];
    __syncthreads();
    float e = (t < 196) ? expf(v - mx) : 0.f;
    red[t] = e;
    __syncthreads();
    for (int s = 128; s > 0; s >>= 1) {
        if (t < s) red[t] += red[t + s];
        __syncthreads();
    }
    if (t < 196) alpha[b * 196 + t] = e / red[0];
}

// context[b,f] = beta[b]/196 * sum_l alpha[b,l]*features[b,l,f] -> xbuf[:,512+f]
__global__ void context_kernel(const float* __restrict__ features,
                               const float* __restrict__ alpha,
                               const float* __restrict__ beta,
                               float* __restrict__ xbuf) {
    int b = blockIdx.y;
    int t = threadIdx.x;
    int f0 = blockIdx.x * 1024 + t * 4;
    __shared__ float sa[196];
    for (int i = t; i < 196; i += 256) sa[i] = alpha[b * 196 + i];
    __syncthreads();
    const float* fb = features + (size_t)b * 196 * 2048 + f0;
    f32x4 accv = (f32x4){0.f, 0.f, 0.f, 0.f};
    for (int l = 0; l < 196; ++l) {
        f32x4 v = *(const f32x4*)(fb + (size_t)l * 2048);
        accv += v * sa[l];
    }
    float scale = beta[b] * (1.0f / 196.0f);
    *(f32x4*)(xbuf + (size_t)b * 2560 + 512 + f0) = accv * scale;
}

// beta[b] = sigmoid(hidden[b,:] . sel_W + sel_b)
__global__ void beta_kernel(const float* __restrict__ hidden, const float* __restrict__ selW,
                            const float* __restrict__ selb, float* __restrict__ beta) {
    int b = blockIdx.x;
    int t = threadIdx.x;  // 256, each handles 4
    const float* h = hidden + (size_t)b * 1024;
    float s = h[t] * selW[t] + h[256 + t] * selW[256 + t] +
              h[512 + t] * selW[512 + t] + h[768 + t] * selW[768 + t];
    __shared__ float red[256];
    red[t] = s;
    __syncthreads();
    for (int k = 128; k > 0; k >>= 1) {
        if (t < k) red[t] += red[t + k];
        __syncthreads();
    }
    if (t == 0) beta[b] = sigf(red[0] + selb[0]);
}

// xbuf[b,0:512] = emb_table[token[b]]
__global__ void embed_kernel(const int* __restrict__ token, const float* __restrict__ emb,
                             float* __restrict__ xbuf) {
    int b = blockIdx.x;
    int t = threadIdx.x;  // 128
    f32x4 v = *(const f32x4*)(emb + (size_t)token[b] * 512 + t * 4);
    *(f32x4*)(xbuf + (size_t)b * 2560 + t * 4) = v;
}

// LSTM pointwise: gate order i,f,g,o
__global__ void lstm_pw(const float* __restrict__ gates, const float* __restrict__ b_ih,
                        const float* __restrict__ b_hh, const float* __restrict__ cell,
                        float* __restrict__ out_h, float* __restrict__ out_c) {
    int idx = blockIdx.x * 256 + threadIdx.x;  // 262144
    int b = idx >> 10, h = idx & 1023;
    const float* g = gates + (size_t)b * 4096;
    float gi = g[h]        + b_ih[h]        + b_hh[h];
    float gf = g[1024 + h] + b_ih[1024 + h] + b_hh[1024 + h];
    float gg = g[2048 + h] + b_ih[2048 + h] + b_hh[2048 + h];
    float go = g[3072 + h] + b_ih[3072 + h] + b_hh[3072 + h];
    float c_new = sigf(gf) * cell[idx] + sigf(gi) * tanhf(gg);
    float h_new = sigf(go) * tanhf(c_new);
    out_c[idx] = c_new;
    out_h[idx] = h_new;
}

extern "C" void kernel_launch(void* const* d_in, const int* in_sizes, int n_in,
                              void* d_out, int out_size, void* d_ws, size_t ws_size,
                              hipStream_t stream) {
    const int*   token     = (const int*)d_in[0];
    const float* features  = (const float*)d_in[1];
    const float* hidden    = (const float*)d_in[2];
    const float* cell      = (const float*)d_in[3];
    const float* emb_table = (const float*)d_in[4];
    const float* att_Wf    = (const float*)d_in[5];
    const float* att_bf    = (const float*)d_in[6];
    const float* att_Wh    = (const float*)d_in[7];
    const float* att_bh    = (const float*)d_in[8];
    const float* att_Wa    = (const float*)d_in[9];
    // d_in[10] att_ba: constant shift, cancels in softmax; score not an output
    const float* sel_W     = (const float*)d_in[11];
    const float* sel_b     = (const float*)d_in[12];
    const float* W_ih      = (const float*)d_in[13];
    const float* b_ih      = (const float*)d_in[14];
    const float* W_hh      = (const float*)d_in[15];
    const float* b_hh      = (const float*)d_in[16];
    const float* deep_W    = (const float*)d_in[17];
    const float* deep_b    = (const float*)d_in[18];

    float* out       = (float*)d_out;
    float* out_logit = out;                       // 256*10000
    float* out_h     = out + 2560000;             // 256*1024
    float* out_c     = out_h + 262144;            // 256*1024
    float* out_alpha = out_c + 262144;            // 256*196

    float* ws       = (float*)d_ws;
    float* hid_proj = ws;                          // 262144
    float* beta     = ws + 262144;                 // 256
    float* score    = ws + 262400;                 // 50176
    float* xbuf     = ws + 312576;                 // 256*2560 = 655360
    float* gates    = ws + 967936;                 // 256*4096 = 1048576

    hipMemsetAsync(score, 0, 50176 * sizeof(float), stream);

    // hid_proj = hidden @ att_Wh^T + att_bh   (M=256,N=1024,K=1024)
    gemm_nt<<<dim3(8, 2), 256, 0, stream>>>(hidden, att_Wh, att_bh, hid_proj,
                                            256, 1024, 1024, 0);
    beta_kernel<<<256, 256, 0, stream>>>(hidden, sel_W, sel_b, beta);
    embed_kernel<<<256, 128, 0, stream>>>(token, emb_table, xbuf);

    // fused attention score (the 210 GFLOP GEMM)
    score_gemm<<<dim3(8, 392), 256, 0, stream>>>(features, att_Wf, att_bf,
                                                 hid_proj, att_Wa, score);
    softmax_alpha<<<256, 256, 0, stream>>>(score, out_alpha);
    context_kernel<<<dim3(2, 256), 256, 0, stream>>>(features, out_alpha, beta, xbuf);

    // gates = x @ W_ih^T ; gates += hidden @ W_hh^T  (biases in lstm_pw)
    gemm_nt<<<dim3(32, 2), 256, 0, stream>>>(xbuf, W_ih, nullptr, gates,
                                             256, 4096, 2560, 0);
    gemm_nt<<<dim3(32, 2), 256, 0, stream>>>(hidden, W_hh, nullptr, gates,
                                             256, 4096, 1024, 1);
    lstm_pw<<<1024, 256, 0, stream>>>(gates, b_ih, b_hh, cell, out_h, out_c);

    // logit = new_h @ deep_W^T + deep_b   (M=256,N=10000,K=1024)
    gemm_nt<<<dim3(79, 2), 256, 0, stream>>>(out_h, deep_W, deep_b, out_logit,
                                             256, 10000, 1024, 0);
}

// Round 2
// 1160.969 us; speedup vs baseline: 1.5899x; 1.5899x over previous
//
#include <hip/hip_runtime.h>
#include <hip/hip_bf16.h>
#include <cstdint>

// ---------------------------------------------------------------------------
// Decoder step, round 2: pre-convert all GEMM operands to bf16 once, then
// m97-style GEMMs with global_load_lds (width=16) staging. Fallback to the
// round-1 f32-staging path if ws_size is too small for the bf16 workspace.
// Outputs: [logit 256x10000][new_h 256x1024][new_c 256x1024][alpha 256x196]
// ---------------------------------------------------------------------------

typedef __attribute__((ext_vector_type(8))) short short8;
typedef __attribute__((ext_vector_type(4))) short short4v;
typedef __attribute__((ext_vector_type(4))) float f32x4;
typedef unsigned short us16;

#define LDT 56   // round-1 fallback LDS stride

static __device__ inline us16 f2bf(float x) {
    uint32_t u = __builtin_bit_cast(uint32_t, x);
    u = (u + 0x7FFFu + ((u >> 16) & 1u)) >> 16;
    return (us16)u;
}
static __device__ inline float bf2f(us16 h) {
    uint32_t u = (uint32_t)h << 16;
    return __builtin_bit_cast(float, u);
}
static __device__ inline uint64_t pack4(f32x4 v) {
    return (uint64_t)f2bf(v.x) | ((uint64_t)f2bf(v.y) << 16) |
           ((uint64_t)f2bf(v.z) << 32) | ((uint64_t)f2bf(v.w) << 48);
}
static __device__ inline float sigf(float x) { return 1.0f / (1.0f + expf(-x)); }

// async global->LDS, 16 B per lane; lds dest = wave-uniform base + lane*16
#define GLOAD_LDS16(gp, lp)                                                \
    __builtin_amdgcn_global_load_lds(                                      \
        (const __attribute__((address_space(1))) void*)(gp),               \
        (__attribute__((address_space(3))) void*)(lp), 16, 0, 0)

// ===========================================================================
// bf16 fast path
// ===========================================================================

// plain f32 -> bf16, 8 elems/thread
__global__ void cvt_plain(const float* __restrict__ src, us16* __restrict__ dst, int n8) {
    int i = blockIdx.x * 256 + threadIdx.x;
    if (i >= n8) return;
    f32x4 a = *(const f32x4*)(src + (size_t)i * 8);
    f32x4 b = *(const f32x4*)(src + (size_t)i * 8 + 4);
    union { uint64_t q[2]; short8 v; } u;
    u.q[0] = pack4(a); u.q[1] = pack4(b);
    *(short8*)(dst + (size_t)i * 8) = u.v;
}

// strided f32 -> bf16: row = blockIdx.x, cols = threadIdx.x*8 .. +7
__global__ void cvt_stride(const float* __restrict__ src, us16* __restrict__ dst, int dstpitch) {
    int row = blockIdx.x;
    int c = threadIdx.x * 8;
    int srcw = blockDim.x * 8;
    f32x4 a = *(const f32x4*)(src + (size_t)row * srcw + c);
    f32x4 b = *(const f32x4*)(src + (size_t)row * srcw + c + 4);
    union { uint64_t q[2]; short8 v; } u;
    u.q[0] = pack4(a); u.q[1] = pack4(b);
    *(short8*)(dst + (size_t)row * dstpitch + c) = u.v;
}

// xcat[b,0:512] = bf16(emb_table[token[b]]); 64 threads x 8 elems
__global__ void embed_bf(const int* __restrict__ token, const float* __restrict__ emb,
                         us16* __restrict__ xcat) {
    int b = blockIdx.x, t = threadIdx.x;
    const float* s = emb + (size_t)token[b] * 512 + t * 8;
    f32x4 a = *(const f32x4*)s;
    f32x4 c = *(const f32x4*)(s + 4);
    union { uint64_t q[2]; short8 v; } u;
    u.q[0] = pack4(a); u.q[1] = pack4(c);
    *(short8*)(xcat + (size_t)b * 3584 + t * 8) = u.v;
}

// ---------------------------------------------------------------------------
// bf16 NT GEMM, 128x128 tile, global_load_lds staging, fused score epilogue:
// score[m] += sum_n relu(acc + bf[n] + hproj[b,n]) * Wa[n]
// A = features_bf16 [50176,2048], W = att_Wf_bf16 [1024,2048]
// ---------------------------------------------------------------------------
__global__ __launch_bounds__(256) void score_gemm_bf(
    const us16* __restrict__ A, const us16* __restrict__ W,
    const float* __restrict__ bfb, const float* __restrict__ hproj,
    const float* __restrict__ Wa, float* __restrict__ score)
{
    const int K = 2048;
    __shared__ us16 As[128 * 32];
    __shared__ us16 Ws[128 * 32];
    const int tid = threadIdx.x, lane = tid & 63, wid = tid >> 6;
    const int wm = (wid >> 1) * 64, wn = (wid & 1) * 64;
    const int m0 = blockIdx.y * 128, n0 = blockIdx.x * 128;
    const int rloc = lane >> 2, seg = lane & 3;

    f32x4 acc[4][4];
#pragma unroll
    for (int i = 0; i < 4; ++i)
#pragma unroll
        for (int j = 0; j < 4; ++j) acc[i][j] = (f32x4){0.f, 0.f, 0.f, 0.f};

    for (int k0 = 0; k0 < K; k0 += 32) {
#pragma unroll
        for (int j = 0; j < 2; ++j) {
            int base = j * 64 + wid * 16;
            int r = base + rloc;
            GLOAD_LDS16(A + (size_t)(m0 + r) * K + k0 + seg * 8, &As[base * 32]);
            GLOAD_LDS16(W + (size_t)(n0 + r) * K + k0 + seg * 8, &Ws[base * 32]);
        }
        __syncthreads();
        const int kq = lane >> 4, fr = lane & 15;
        short8 af[4], bw[4];
#pragma unroll
        for (int mi = 0; mi < 4; ++mi)
            af[mi] = *(const short8*)&As[(wm + mi * 16 + fr) * 32 + kq * 8];
#pragma unroll
        for (int ni = 0; ni < 4; ++ni)
            bw[ni] = *(const short8*)&Ws[(wn + ni * 16 + fr) * 32 + kq * 8];
#pragma unroll
        for (int mi = 0; mi < 4; ++mi)
#pragma unroll
            for (int ni = 0; ni < 4; ++ni)
                acc[mi][ni] = __builtin_amdgcn_mfma_f32_16x16x32_bf16(
                    af[mi], bw[ni], acc[mi][ni], 0, 0, 0);
        __syncthreads();
    }
    const int cr = (lane >> 4) * 4, cc = lane & 15;
#pragma unroll
    for (int mi = 0; mi < 4; ++mi)
#pragma unroll
        for (int r = 0; r < 4; ++r) {
            int gm = m0 + wm + mi * 16 + cr + r;
            int b = gm / 196;
            float s = 0.f;
#pragma unroll
            for (int ni = 0; ni < 4; ++ni) {
                int gn = n0 + wn + ni * 16 + cc;
                float v = acc[mi][ni][r] + bfb[gn] + hproj[b * 1024 + gn];
                v = fmaxf(v, 0.f);
                s += v * Wa[gn];
            }
            s += __shfl_xor(s, 1);
            s += __shfl_xor(s, 2);
            s += __shfl_xor(s, 4);
            s += __shfl_xor(s, 8);
            if (cc == 0) atomicAdd(&score[gm], s);
        }
}

// ---------------------------------------------------------------------------
// bf16 NT GEMM, 64x128 tile (4x more blocks for M=256 shapes):
// C[m,n] = A[m,:].W[n,:] (+bias). A row stride lda, W row stride ldw.
// ---------------------------------------------------------------------------
__global__ __launch_bounds__(256) void gemm_bf_sm(
    const us16* __restrict__ A, int lda,
    const us16* __restrict__ W, int ldw,
    const float* __restrict__ bias, float* __restrict__ C,
    int M, int N, int K)
{
    __shared__ us16 As[64 * 32];
    __shared__ us16 Ws[128 * 32];
    const int tid = threadIdx.x, lane = tid & 63, wid = tid >> 6;
    const int wm = (wid >> 1) * 32, wn = (wid & 1) * 64;
    const int m0 = blockIdx.y * 64, n0 = blockIdx.x * 128;
    const int rloc = lane >> 2, seg = lane & 3;

    f32x4 acc[2][4];
#pragma unroll
    for (int i = 0; i < 2; ++i)
#pragma unroll
        for (int j = 0; j < 4; ++j) acc[i][j] = (f32x4){0.f, 0.f, 0.f, 0.f};

    for (int k0 = 0; k0 < K; k0 += 32) {
        {
            int r = wid * 16 + rloc;
            int gr = m0 + r; if (gr >= M) gr = M - 1;
            GLOAD_LDS16(A + (size_t)gr * lda + k0 + seg * 8, &As[(wid * 16) * 32]);
        }
#pragma unroll
        for (int j = 0; j < 2; ++j) {
            int base = j * 64 + wid * 16;
            int gr = n0 + base + rloc; if (gr >= N) gr = N - 1;
            GLOAD_LDS16(W + (size_t)gr * ldw + k0 + seg * 8, &Ws[base * 32]);
        }
        __syncthreads();
        const int kq = lane >> 4, fr = lane & 15;
        short8 af[2], bw[4];
#pragma unroll
        for (int mi = 0; mi < 2; ++mi)
            af[mi] = *(const short8*)&As[(wm + mi * 16 + fr) * 32 + kq * 8];
#pragma unroll
        for (int ni = 0; ni < 4; ++ni)
            bw[ni] = *(const short8*)&Ws[(wn + ni * 16 + fr) * 32 + kq * 8];
#pragma unroll
        for (int mi = 0; mi < 2; ++mi)
#pragma unroll
            for (int ni = 0; ni < 4; ++ni)
                acc[mi][ni] = __builtin_amdgcn_mfma_f32_16x16x32_bf16(
                    af[mi], bw[ni], acc[mi][ni], 0, 0, 0);
        __syncthreads();
    }
    const int cr = (lane >> 4) * 4, cc = lane & 15;
#pragma unroll
    for (int mi = 0; mi < 2; ++mi)
#pragma unroll
        for (int ni = 0; ni < 4; ++ni) {
            int gn = n0 + wn + ni * 16 + cc;
#pragma unroll
            for (int r = 0; r < 4; ++r) {
                int gm = m0 + wm + mi * 16 + cr + r;
                if (gm < M && gn < N) {
                    float v = acc[mi][ni][r];
                    if (bias) v += bias[gn];
                    C[(size_t)gm * N + gn] = v;
                }
            }
        }
}

// context (bf16 features) -> bf16 into xcat[:,512:2560]; 4 cols/thread
__global__ void context_bf(const us16* __restrict__ fbf, const float* __restrict__ alpha,
                           const float* __restrict__ beta, us16* __restrict__ xcat) {
    int b = blockIdx.y, t = threadIdx.x;
    int f0 = blockIdx.x * 1024 + t * 4;
    __shared__ float sa[196];
    for (int i = t; i < 196; i += 256) sa[i] = alpha[b * 196 + i];
    __syncthreads();
    const us16* fb = fbf + (size_t)b * 196 * 2048 + f0;
    f32x4 accv = (f32x4){0.f, 0.f, 0.f, 0.f};
    for (int l = 0; l < 196; ++l) {
        short4v v = *(const short4v*)(fb + (size_t)l * 2048);
        float a = sa[l];
        accv.x += bf2f((us16)v.x) * a;
        accv.y += bf2f((us16)v.y) * a;
        accv.z += bf2f((us16)v.z) * a;
        accv.w += bf2f((us16)v.w) * a;
    }
    float scale = beta[b] * (1.0f / 196.0f);
    accv *= scale;
    *(uint64_t*)(xcat + (size_t)b * 3584 + 512 + f0) = pack4(accv);
}

// LSTM pointwise + bf16 copy of new_h
__global__ void lstm_pw2(const float* __restrict__ gates, const float* __restrict__ b_ih,
                         const float* __restrict__ b_hh, const float* __restrict__ cell,
                         float* __restrict__ out_h, float* __restrict__ out_c,
                         us16* __restrict__ h_bf) {
    int idx = blockIdx.x * 256 + threadIdx.x;
    int b = idx >> 10, h = idx & 1023;
    const float* g = gates + (size_t)b * 4096;
    float gi = g[h]        + b_ih[h]        + b_hh[h];
    float gf = g[1024 + h] + b_ih[1024 + h] + b_hh[1024 + h];
    float gg = g[2048 + h] + b_ih[2048 + h] + b_hh[2048 + h];
    float go = g[3072 + h] + b_ih[3072 + h] + b_hh[3072 + h];
    float c_new = sigf(gf) * cell[idx] + sigf(gi) * tanhf(gg);
    float h_new = sigf(go) * tanhf(c_new);
    out_c[idx] = c_new;
    out_h[idx] = h_new;
    h_bf[idx] = f2bf(h_new);
}

// softmax over L=196 per batch row -> alpha
__global__ void softmax_alpha(const float* __restrict__ score, float* __restrict__ alpha) {
    int b = blockIdx.x, t = threadIdx.x;
    __shared__ float red[256];
    float v = (t < 196) ? score[b * 196 + t] : -1e30f;
    red[t] = v;
    __syncthreads();
    for (int s = 128; s > 0; s >>= 1) {
        if (t < s) red[t] = fmaxf(red[t], red[t + s]);
        __syncthreads();
    }
    float mx = red[0];
    __syncthreads();
    float e = (t < 196) ? expf(v - mx) : 0.f;
    red[t] = e;
    __syncthreads();
    for (int s = 128; s > 0; s >>= 1) {
        if (t < s) red[t] += red[t + s];
        __syncthreads();
    }
    if (t < 196) alpha[b * 196 + t] = e / red[0];
}

// beta[b] = sigmoid(hidden[b,:] . sel_W + sel_b)
__global__ void beta_kernel(const float* __restrict__ hidden, const float* __restrict__ selW,
                            const float* __restrict__ selb, float* __restrict__ beta) {
    int b = blockIdx.x, t = threadIdx.x;
    const float* h = hidden + (size_t)b * 1024;
    float s = h[t] * selW[t] + h[256 + t] * selW[256 + t] +
              h[512 + t] * selW[512 + t] + h[768 + t] * selW[768 + t];
    __shared__ float red[256];
    red[t] = s;
    __syncthreads();
    for (int k = 128; k > 0; k >>= 1) {
        if (t < k) red[t] += red[t + k];
        __syncthreads();
    }
    if (t == 0) beta[b] = sigf(red[0] + selb[0]);
}

// ===========================================================================
// Round-1 f32-staging fallback (used only if ws_size < bf16 workspace need)
// ===========================================================================
__global__ __launch_bounds__(256) void gemm_nt(
    const float* __restrict__ A, const float* __restrict__ W,
    const float* __restrict__ bias, float* __restrict__ C,
    int M, int N, int K, int accflag)
{
    __shared__ us16 As[128 * LDT];
    __shared__ us16 Ws[128 * LDT];
    const int tid = threadIdx.x, lane = tid & 63, wid = tid >> 6;
    const int wm = (wid >> 1) * 64, wn = (wid & 1) * 64;
    const int m0 = blockIdx.y * 128, n0 = blockIdx.x * 128;
    f32x4 acc[4][4];
#pragma unroll
    for (int i = 0; i < 4; ++i)
#pragma unroll
        for (int j = 0; j < 4; ++j) acc[i][j] = (f32x4){0.f, 0.f, 0.f, 0.f};
    for (int k0 = 0; k0 < K; k0 += 32) {
#pragma unroll
        for (int i = 0; i < 4; ++i) {
            int idx = i * 256 + tid;
            int rr = idx >> 3, cq = idx & 7;
            int gm = m0 + rr;
            f32x4 va = (f32x4){0.f, 0.f, 0.f, 0.f};
            if (gm < M) va = *(const f32x4*)(A + (size_t)gm * K + k0 + cq * 4);
            *(uint64_t*)&As[rr * LDT + cq * 4] = pack4(va);
            int gn = n0 + rr;
            f32x4 vb = (f32x4){0.f, 0.f, 0.f, 0.f};
            if (gn < N) vb = *(const f32x4*)(W + (size_t)gn * K + k0 + cq * 4);
            *(uint64_t*)&Ws[rr * LDT + cq * 4] = pack4(vb);
        }
        __syncthreads();
        const int kq = lane >> 4, fr = lane & 15;
        short8 af[4], bw[4];
#pragma unroll
        for (int mi = 0; mi < 4; ++mi)
            af[mi] = *(const short8*)&As[(wm + mi * 16 + fr) * LDT + kq * 8];
#pragma unroll
        for (int ni = 0; ni < 4; ++ni)
            bw[ni] = *(const short8*)&Ws[(wn + ni * 16 + fr) * LDT + kq * 8];
#pragma unroll
        for (int mi = 0; mi < 4; ++mi)
#pragma unroll
            for (int ni = 0; ni < 4; ++ni)
                acc[mi][ni] = __builtin_amdgcn_mfma_f32_16x16x32_bf16(
                    af[mi], bw[ni], acc[mi][ni], 0, 0, 0);
        __syncthreads();
    }
    const int cr = (lane >> 4) * 4, cc = lane & 15;
#pragma unroll
    for (int mi = 0; mi < 4; ++mi)
#pragma unroll
        for (int ni = 0; ni < 4; ++ni) {
            int gn = n0 + wn + ni * 16 + cc;
#pragma unroll
            for (int r = 0; r < 4; ++r) {
                int gm = m0 + wm + mi * 16 + cr + r;
                if (gm < M && gn < N) {
                    float v = acc[mi][ni][r];
                    if (bias) v += bias[gn];
                    if (accflag) v += C[(size_t)gm * N + gn];
                    C[(size_t)gm * N + gn] = v;
                }
            }
        }
}

__global__ __launch_bounds__(256) void score_gemm_f32(
    const float* __restrict__ A, const float* __restrict__ W,
    const float* __restrict__ bfb, const float* __restrict__ hproj,
    const float* __restrict__ Wa, float* __restrict__ score)
{
    const int K = 2048;
    __shared__ us16 As[128 * LDT];
    __shared__ us16 Ws[128 * LDT];
    const int tid = threadIdx.x, lane = tid & 63, wid = tid >> 6;
    const int wm = (wid >> 1) * 64, wn = (wid & 1) * 64;
    const int m0 = blockIdx.y * 128, n0 = blockIdx.x * 128;
    f32x4 acc[4][4];
#pragma unroll
    for (int i = 0; i < 4; ++i)
#pragma unroll
        for (int j = 0; j < 4; ++j) acc[i][j] = (f32x4){0.f, 0.f, 0.f, 0.f};
    for (int k0 = 0; k0 < K; k0 += 32) {
#pragma unroll
        for (int i = 0; i < 4; ++i) {
            int idx = i * 256 + tid;
            int rr = idx >> 3, cq = idx & 7;
            f32x4 va = *(const f32x4*)(A + (size_t)(m0 + rr) * K + k0 + cq * 4);
            *(uint64_t*)&As[rr * LDT + cq * 4] = pack4(va);
            f32x4 vb = *(const f32x4*)(W + (size_t)(n0 + rr) * K + k0 + cq * 4);
            *(uint64_t*)&Ws[rr * LDT + cq * 4] = pack4(vb);
        }
        __syncthreads();
        const int kq = lane >> 4, fr = lane & 15;
        short8 af[4], bw[4];
#pragma unroll
        for (int mi = 0; mi < 4; ++mi)
            af[mi] = *(const short8*)&As[(wm + mi * 16 + fr) * LDT + kq * 8];
#pragma unroll
        for (int ni = 0; ni < 4; ++ni)
            bw[ni] = *(const short8*)&Ws[(wn + ni * 16 + fr) * LDT + kq * 8];
#pragma unroll
        for (int mi = 0; mi < 4; ++mi)
#pragma unroll
            for (int ni = 0; ni < 4; ++ni)
                acc[mi][ni] = __builtin_amdgcn_mfma_f32_16x16x32_bf16(
                    af[mi], bw[ni], acc[mi][ni], 0, 0, 0);
        __syncthreads();
    }
    const int cr = (lane >> 4) * 4, cc = lane & 15;
#pragma unroll
    for (int mi = 0; mi < 4; ++mi)
#pragma unroll
        for (int r = 0; r < 4; ++r) {
            int gm = m0 + wm + mi * 16 + cr + r;
            int b = gm / 196;
            float s = 0.f;
#pragma unroll
            for (int ni = 0; ni < 4; ++ni) {
                int gn = n0 + wn + ni * 16 + cc;
                float v = acc[mi][ni][r] + bfb[gn] + hproj[b * 1024 + gn];
                v = fmaxf(v, 0.f);
                s += v * Wa[gn];
            }
            s += __shfl_xor(s, 1);
            s += __shfl_xor(s, 2);
            s += __shfl_xor(s, 4);
            s += __shfl_xor(s, 8);
            if (cc == 0) atomicAdd(&score[gm], s);
        }
}

__global__ void context_f32(const float* __restrict__ features, const float* __restrict__ alpha,
                            const float* __restrict__ beta, float* __restrict__ xbuf) {
    int b = blockIdx.y, t = threadIdx.x;
    int f0 = blockIdx.x * 1024 + t * 4;
    __shared__ float sa[196];
    for (int i = t; i < 196; i += 256) sa[i] = alpha[b * 196 + i];
    __syncthreads();
    const float* fb = features + (size_t)b * 196 * 2048 + f0;
    f32x4 accv = (f32x4){0.f, 0.f, 0.f, 0.f};
    for (int l = 0; l < 196; ++l) {
        f32x4 v = *(const f32x4*)(fb + (size_t)l * 2048);
        accv += v * sa[l];
    }
    float scale = beta[b] * (1.0f / 196.0f);
    *(f32x4*)(xbuf + (size_t)b * 2560 + 512 + f0) = accv * scale;
}

__global__ void embed_f32(const int* __restrict__ token, const float* __restrict__ emb,
                          float* __restrict__ xbuf) {
    int b = blockIdx.x, t = threadIdx.x;
    f32x4 v = *(const f32x4*)(emb + (size_t)token[b] * 512 + t * 4);
    *(f32x4*)(xbuf + (size_t)b * 2560 + t * 4) = v;
}

__global__ void lstm_pw(const float* __restrict__ gates, const float* __restrict__ b_ih,
                        const float* __restrict__ b_hh, const float* __restrict__ cell,
                        float* __restrict__ out_h, float* __restrict__ out_c) {
    int idx = blockIdx.x * 256 + threadIdx.x;
    int b = idx >> 10, h = idx & 1023;
    const float* g = gates + (size_t)b * 4096;
    float gi = g[h]        + b_ih[h]        + b_hh[h];
    float gf = g[1024 + h] + b_ih[1024 + h] + b_hh[1024 + h];
    float gg = g[2048 + h] + b_ih[2048 + h] + b_hh[2048 + h];
    float go = g[3072 + h] + b_ih[3072 + h] + b_hh[3072 + h];
    float c_new = sigf(gf) * cell[idx] + sigf(gi) * tanhf(gg);
    float h_new = sigf(go) * tanhf(c_new);
    out_c[idx] = c_new;
    out_h[idx] = h_new;
}

// ===========================================================================
extern "C" void kernel_launch(void* const* d_in, const int* in_sizes, int n_in,
                              void* d_out, int out_size, void* d_ws, size_t ws_size,
                              hipStream_t stream) {
    const int*   token     = (const int*)d_in[0];
    const float* features  = (const float*)d_in[1];
    const float* hidden    = (const float*)d_in[2];
    const float* cell      = (const float*)d_in[3];
    const float* emb_table = (const float*)d_in[4];
    const float* att_Wf    = (const float*)d_in[5];
    const float* att_bf    = (const float*)d_in[6];
    const float* att_Wh    = (const float*)d_in[7];
    const float* att_bh    = (const float*)d_in[8];
    const float* att_Wa    = (const float*)d_in[9];
    // d_in[10] att_ba: cancels in softmax
    const float* sel_W     = (const float*)d_in[11];
    const float* sel_b     = (const float*)d_in[12];
    const float* W_ih      = (const float*)d_in[13];
    const float* b_ih      = (const float*)d_in[14];
    const float* W_hh      = (const float*)d_in[15];
    const float* b_hh      = (const float*)d_in[16];
    const float* deep_W    = (const float*)d_in[17];
    const float* deep_b    = (const float*)d_in[18];

    float* out       = (float*)d_out;
    float* out_logit = out;
    float* out_h     = out + 2560000;
    float* out_c     = out_h + 262144;
    float* out_alpha = out_c + 262144;

    // bf16 workspace layout (bytes)
    const size_t OFF_FBF   = 0;                       // 205,520,896
    const size_t OFF_WF    = OFF_FBF   + 205520896;   // 4,194,304
    const size_t OFF_WH    = OFF_WF    + 4194304;     // 2,097,152
    const size_t OFF_WCAT  = OFF_WH    + 2097152;     // 29,360,128
    const size_t OFF_WDEEP = OFF_WCAT  + 29360128;    // 20,480,000
    const size_t OFF_XCAT  = OFF_WDEEP + 20480000;    // 1,835,008
    const size_t OFF_HBF   = OFF_XCAT  + 1835008;     // 524,288
    const size_t OFF_HPROJ = OFF_HBF   + 524288;      // 1,048,576
    const size_t OFF_BETA  = OFF_HPROJ + 1048576;     // 1,024
    const size_t OFF_SCORE = OFF_BETA  + 1024;        // 200,704
    const size_t OFF_GATES = OFF_SCORE + 200704;      // 4,194,304
    const size_t NEED      = OFF_GATES + 4194304;     // ~269.5 MB

    if (ws_size >= NEED) {
        char* w = (char*)d_ws;
        us16*  fbf      = (us16*)(w + OFF_FBF);
        us16*  wf_bf    = (us16*)(w + OFF_WF);
        us16*  wh_bf    = (us16*)(w + OFF_WH);
        us16*  wcat_bf  = (us16*)(w + OFF_WCAT);
        us16*  wdeep_bf = (us16*)(w + OFF_WDEEP);
        us16*  xcat     = (us16*)(w + OFF_XCAT);
        us16*  h_bf     = (us16*)(w + OFF_HBF);
        float* hid_proj = (float*)(w + OFF_HPROJ);
        float* beta     = (float*)(w + OFF_BETA);
        float* score    = (float*)(w + OFF_SCORE);
        float* gates    = (float*)(w + OFF_GATES);

        // conversions
        cvt_plain<<<50176, 256, 0, stream>>>(features, fbf, 12845056);
        cvt_plain<<<1024, 256, 0, stream>>>(att_Wf, wf_bf, 262144);
        cvt_plain<<<512, 256, 0, stream>>>(att_Wh, wh_bf, 131072);
        cvt_plain<<<5000, 256, 0, stream>>>(deep_W, wdeep_bf, 1280000);
        cvt_stride<<<4096, 320, 0, stream>>>(W_ih, wcat_bf, 3584);        // cols 0:2560
        cvt_stride<<<4096, 128, 0, stream>>>(W_hh, wcat_bf + 2560, 3584); // cols 2560:3584
        cvt_stride<<<256, 128, 0, stream>>>(hidden, xcat + 2560, 3584);   // hidden slice
        embed_bf<<<256, 64, 0, stream>>>(token, emb_table, xcat);
        beta_kernel<<<256, 256, 0, stream>>>(hidden, sel_W, sel_b, beta);
        hipMemsetAsync(score, 0, 200704, stream);

        // hid_proj = hidden @ att_Wh^T + att_bh
        gemm_bf_sm<<<dim3(8, 4), 256, 0, stream>>>(xcat + 2560, 3584, wh_bf, 1024,
                                                   att_bh, hid_proj, 256, 1024, 1024);
        // fused attention score GEMM (210 GFLOP)
        score_gemm_bf<<<dim3(8, 392), 256, 0, stream>>>(fbf, wf_bf, att_bf,
                                                        hid_proj, att_Wa, score);
        softmax_alpha<<<256, 256, 0, stream>>>(score, out_alpha);
        context_bf<<<dim3(2, 256), 256, 0, stream>>>(fbf, out_alpha, beta, xcat);

        // gates = [emb|ctx|hid] @ [W_ih|W_hh]^T  (single K=3584 GEMM)
        gemm_bf_sm<<<dim3(32, 4), 256, 0, stream>>>(xcat, 3584, wcat_bf, 3584,
                                                    nullptr, gates, 256, 4096, 3584);
        lstm_pw2<<<1024, 256, 0, stream>>>(gates, b_ih, b_hh, cell, out_h, out_c, h_bf);

        // logit = new_h @ deep_W^T + deep_b
        gemm_bf_sm<<<dim3(79, 4), 256, 0, stream>>>(h_bf, 1024, wdeep_bf, 1024,
                                                    deep_b, out_logit, 256, 10000, 1024);
    } else {
        // -------- round-1 fallback (small ws) --------
        float* ws       = (float*)d_ws;
        float* hid_proj = ws;
        float* beta     = ws + 262144;
        float* score    = ws + 262400;
        float* xbuf     = ws + 312576;
        float* gates    = ws + 967936;

        hipMemsetAsync(score, 0, 50176 * sizeof(float), stream);
        gemm_nt<<<dim3(8, 2), 256, 0, stream>>>(hidden, att_Wh, att_bh, hid_proj,
                                                256, 1024, 1024, 0);
        beta_kernel<<<256, 256, 0, stream>>>(hidden, sel_W, sel_b, beta);
        embed_f32<<<256, 128, 0, stream>>>(token, emb_table, xbuf);
        score_gemm_f32<<<dim3(8, 392), 256, 0, stream>>>(features, att_Wf, att_bf,
                                                         hid_proj, att_Wa, score);
        softmax_alpha<<<256, 256, 0, stream>>>(score, out_alpha);
        context_f32<<<dim3(2, 256), 256, 0, stream>>>(features, out_alpha, beta, xbuf);
        gemm_nt<<<dim3(32, 2), 256, 0, stream>>>(xbuf, W_ih, nullptr, gates,
                                                 256, 4096, 2560, 0);
        gemm_nt<<<dim3(32, 2), 256, 0, stream>>>(hidden, W_hh, nullptr, gates,
                                                 256, 4096, 1024, 1);
        lstm_pw<<<1024, 256, 0, stream>>>(gates, b_ih, b_hh, cell, out_h, out_c);
        gemm_nt<<<dim3(79, 2), 256, 0, stream>>>(out_h, deep_W, deep_b, out_logit,
                                                 256, 10000, 1024, 0);
    }
}